// Round 1
// baseline (411.623 us; speedup 1.0000x reference)
//
#include <hip/hip_runtime.h>
#include <math.h>

#define BATCH 16384
#define N_CTX 10
#define N_NEG 20
#define DIM 300            // 75 float4 per row
#define WAVES_PER_BLOCK 4
#define NBLOCKS (BATCH / WAVES_PER_BLOCK)   // 4096

__device__ __forceinline__ float wave_reduce_sum(float v) {
#pragma unroll
    for (int m = 32; m >= 1; m >>= 1)
        v += __shfl_xor(v, m, 64);
    return v;
}

// numerically-stable log(sigmoid(x)) = min(x,0) - log1p(exp(-|x|))
__device__ __forceinline__ float log_sigmoid(float x) {
    return fminf(x, 0.0f) - log1pf(__expf(-fabsf(x)));
}

__device__ __forceinline__ float dot4(float4 a, float4 b) {
    return a.x * b.x + a.y * b.y + a.z * b.z + a.w * b.w;
}

__global__ __launch_bounds__(256) void cbow_loss_kernel(
    const int* __restrict__ context,     // [B, N_CTX]
    const int* __restrict__ center,      // [B]
    const int* __restrict__ negatives,   // [B, N_NEG]
    const float* __restrict__ ctx_w,     // [V, DIM]
    const float* __restrict__ cen_w,     // [V, DIM]
    float* __restrict__ partials)        // [NBLOCKS]
{
    const int wave = threadIdx.x >> 6;
    const int lane = threadIdx.x & 63;
    const int b    = blockIdx.x * WAVES_PER_BLOCK + wave;

    // lane's two float4 slots within a 75-float4 row
    const int  p0   = lane;        // always valid (0..63)
    const int  p1   = 64 + lane;   // valid for lane < 11 (64..74)
    const bool has1 = (lane < 11);
    const float4 z4 = make_float4(0.f, 0.f, 0.f, 0.f);

    // ---- context mean (sum of 10 gathered rows, then *0.1) ----
    float4 m0 = z4, m1 = z4;
#pragma unroll
    for (int j = 0; j < N_CTX; ++j) {
        const int idx = context[b * N_CTX + j];
        const float4* row = (const float4*)(ctx_w + (size_t)idx * DIM);
        float4 r0 = row[p0];
        float4 r1 = has1 ? row[p1] : z4;
        m0.x += r0.x; m0.y += r0.y; m0.z += r0.z; m0.w += r0.w;
        m1.x += r1.x; m1.y += r1.y; m1.z += r1.z; m1.w += r1.w;
    }
    m0.x *= 0.1f; m0.y *= 0.1f; m0.z *= 0.1f; m0.w *= 0.1f;
    m1.x *= 0.1f; m1.y *= 0.1f; m1.z *= 0.1f; m1.w *= 0.1f;

    // ---- positive score ----
    {
        const int cidx = center[b];
        const float4* crow = (const float4*)(cen_w + (size_t)cidx * DIM);
        float4 c0 = crow[p0];
        float4 c1 = has1 ? crow[p1] : z4;
        float part = dot4(m0, c0) + dot4(m1, c1);
        float pos_score = wave_reduce_sum(part);

        // ---- negative scores: per-lane partials first (lets loads pipeline) ----
        float neg_part[N_NEG];
#pragma unroll
        for (int n = 0; n < N_NEG; ++n) {
            const int nidx = negatives[b * N_NEG + n];
            const float4* nrow = (const float4*)(cen_w + (size_t)nidx * DIM);
            float4 r0 = nrow[p0];
            float4 r1 = has1 ? nrow[p1] : z4;
            neg_part[n] = dot4(m0, r0) + dot4(m1, r1);
        }

        float loss = log_sigmoid(pos_score);
#pragma unroll
        for (int n = 0; n < N_NEG; ++n) {
            float ns = wave_reduce_sum(neg_part[n]);
            loss += log_sigmoid(-ns);
        }
        loss = -loss;   // per-element loss

        // ---- block partial via LDS (4 waves) ----
        __shared__ float s_loss[WAVES_PER_BLOCK];
        if (lane == 0) s_loss[wave] = loss;
        __syncthreads();
        if (threadIdx.x == 0) {
            partials[blockIdx.x] = s_loss[0] + s_loss[1] + s_loss[2] + s_loss[3];
        }
    }
}

__global__ __launch_bounds__(256) void reduce_partials_kernel(
    const float* __restrict__ partials, float* __restrict__ out)
{
    __shared__ double smem[256];
    double acc = 0.0;
    for (int i = threadIdx.x; i < NBLOCKS; i += 256) acc += (double)partials[i];
    smem[threadIdx.x] = acc;
    __syncthreads();
    for (int s = 128; s > 0; s >>= 1) {
        if ((int)threadIdx.x < s) smem[threadIdx.x] += smem[threadIdx.x + s];
        __syncthreads();
    }
    if (threadIdx.x == 0) out[0] = (float)(smem[0] * (1.0 / (double)BATCH));
}

extern "C" void kernel_launch(void* const* d_in, const int* in_sizes, int n_in,
                              void* d_out, int out_size, void* d_ws, size_t ws_size,
                              hipStream_t stream) {
    const int*   context   = (const int*)d_in[0];
    const int*   center    = (const int*)d_in[1];
    const int*   negatives = (const int*)d_in[2];
    const float* ctx_w     = (const float*)d_in[3];
    const float* cen_w     = (const float*)d_in[4];
    float*       out       = (float*)d_out;
    float*       partials  = (float*)d_ws;   // 4096 floats = 16 KB

    cbow_loss_kernel<<<NBLOCKS, 256, 0, stream>>>(
        context, center, negatives, ctx_w, cen_w, partials);
    reduce_partials_kernel<<<1, 256, 0, stream>>>(partials, out);
}

// Round 2
// 299.207 us; speedup vs baseline: 1.3757x; 1.3757x over previous
//
#include <hip/hip_runtime.h>
#include <math.h>

#define BATCH 16384
#define N_CTX 10
#define N_NEG 20
#define DIM 300            // 64 float4 (256 floats) + 44-float tail
#define WAVES_PER_BLOCK 4
#define NBLOCKS (BATCH / WAVES_PER_BLOCK)   // 4096

__device__ __forceinline__ float wave_reduce_sum(float v) {
#pragma unroll
    for (int m = 32; m >= 1; m >>= 1)
        v += __shfl_xor(v, m, 64);
    return v;
}

// log(sigmoid(x)): degree-4 series around 0 (|err|<1e-5 for |x|<0.5),
// exact stable form as fallback. Scores here are O(1e-3) by construction.
__device__ __forceinline__ float log_sigmoid_f(float x) {
    float ax = fabsf(x);
    if (ax < 0.5f) {
        float x2 = x * x;
        return -0.6931471805599453f + 0.5f * x + x2 * (-0.125f + x2 * (1.0f / 192.0f));
    }
    return fminf(x, 0.0f) - log1pf(__expf(-ax));
}

__device__ __forceinline__ float dot4(float4 a, float4 b) {
    return a.x * b.x + a.y * b.y + a.z * b.z + a.w * b.w;
}

__global__ __launch_bounds__(256) void cbow_loss_kernel(
    const int* __restrict__ context,     // [B, N_CTX]
    const int* __restrict__ center,      // [B]
    const int* __restrict__ negatives,   // [B, N_NEG]
    const float* __restrict__ ctx_w,     // [V, DIM]
    const float* __restrict__ cen_w,     // [V, DIM]
    float* __restrict__ partials)        // [NBLOCKS]
{
    const int wave = threadIdx.x >> 6;
    const int lane = threadIdx.x & 63;
    const int b    = blockIdx.x * WAVES_PER_BLOCK + wave;

    // ---- all 31 indices in 3 lane-parallel loads (no serial idx chain) ----
    int idx_ctx = 0, idx_cen = 0, idx_neg = 0;
    if (lane < N_CTX) idx_ctx = context[b * N_CTX + lane];
    if (lane == 0)    idx_cen = center[b];
    if (lane < N_NEG) idx_neg = negatives[b * N_NEG + lane];

    const bool has_tail = (lane < DIM - 256);   // 44 tail floats, lanes 0..43
    const int  voff4    = lane * 4;              // float4 slot -> element offset
    const int  vofft    = 256 + lane;            // tail element offset

    // ---- issue ctx rows (10), center, neg group A (10): ~21 rows in flight ----
    float4 ar[N_CTX]; float at[N_CTX];
#pragma unroll
    for (int j = 0; j < N_CTX; ++j) {
        int s = __builtin_amdgcn_readlane(idx_ctx, j);      // SGPR index
        const float* rowp = ctx_w + (size_t)s * DIM;
        ar[j] = *(const float4*)(rowp + voff4);
        at[j] = has_tail ? rowp[vofft] : 0.0f;
    }

    {
        int s = __builtin_amdgcn_readlane(idx_cen, 0);
        const float* crow = cen_w + (size_t)s * DIM;
        float4 c4 = *(const float4*)(crow + voff4);
        float  ct = has_tail ? crow[vofft] : 0.0f;

        float4 nr[10]; float nt[10];
#pragma unroll
        for (int n = 0; n < 10; ++n) {
            int sn = __builtin_amdgcn_readlane(idx_neg, n);
            const float* rowp = cen_w + (size_t)sn * DIM;
            nr[n] = *(const float4*)(rowp + voff4);
            nt[n] = has_tail ? rowp[vofft] : 0.0f;
        }

        // ---- consume ctx -> mean ----
        float4 m4 = make_float4(0.f, 0.f, 0.f, 0.f);
        float  mt = 0.f;
#pragma unroll
        for (int j = 0; j < N_CTX; ++j) {
            m4.x += ar[j].x; m4.y += ar[j].y; m4.z += ar[j].z; m4.w += ar[j].w;
            mt   += at[j];
        }
        m4.x *= 0.1f; m4.y *= 0.1f; m4.z *= 0.1f; m4.w *= 0.1f;
        mt *= 0.1f;

        float parts[N_NEG + 1];
        parts[N_NEG] = dot4(m4, c4) + mt * ct;              // positive score
#pragma unroll
        for (int n = 0; n < 10; ++n)
            parts[n] = dot4(m4, nr[n]) + mt * nt[n];

        // ---- neg group B reuses nr/nt registers ----
#pragma unroll
        for (int n = 10; n < N_NEG; ++n) {
            int sn = __builtin_amdgcn_readlane(idx_neg, n);
            const float* rowp = cen_w + (size_t)sn * DIM;
            nr[n - 10] = *(const float4*)(rowp + voff4);
            nt[n - 10] = has_tail ? rowp[vofft] : 0.0f;
        }
#pragma unroll
        for (int n = 10; n < N_NEG; ++n)
            parts[n] = dot4(m4, nr[n - 10]) + mt * nt[n - 10];

        // ---- reductions + loss ----
        float pos = wave_reduce_sum(parts[N_NEG]);
        float loss = log_sigmoid_f(pos);
#pragma unroll
        for (int n = 0; n < N_NEG; ++n) {
            float ns = wave_reduce_sum(parts[n]);
            loss += log_sigmoid_f(-ns);
        }
        loss = -loss;

        __shared__ float s_loss[WAVES_PER_BLOCK];
        if (lane == 0) s_loss[wave] = loss;
        __syncthreads();
        if (threadIdx.x == 0)
            partials[blockIdx.x] = s_loss[0] + s_loss[1] + s_loss[2] + s_loss[3];
    }
}

__global__ __launch_bounds__(256) void reduce_partials_kernel(
    const float* __restrict__ partials, float* __restrict__ out)
{
    __shared__ double smem[256];
    double acc = 0.0;
    for (int i = threadIdx.x; i < NBLOCKS; i += 256) acc += (double)partials[i];
    smem[threadIdx.x] = acc;
    __syncthreads();
    for (int s = 128; s > 0; s >>= 1) {
        if ((int)threadIdx.x < s) smem[threadIdx.x] += smem[threadIdx.x + s];
        __syncthreads();
    }
    if (threadIdx.x == 0) out[0] = (float)(smem[0] * (1.0 / (double)BATCH));
}

extern "C" void kernel_launch(void* const* d_in, const int* in_sizes, int n_in,
                              void* d_out, int out_size, void* d_ws, size_t ws_size,
                              hipStream_t stream) {
    const int*   context   = (const int*)d_in[0];
    const int*   center    = (const int*)d_in[1];
    const int*   negatives = (const int*)d_in[2];
    const float* ctx_w     = (const float*)d_in[3];
    const float* cen_w     = (const float*)d_in[4];
    float*       out       = (float*)d_out;
    float*       partials  = (float*)d_ws;   // 4096 floats = 16 KB

    cbow_loss_kernel<<<NBLOCKS, 256, 0, stream>>>(
        context, center, negatives, ctx_w, cen_w, partials);
    reduce_partials_kernel<<<1, 256, 0, stream>>>(partials, out);
}